// Round 4
// baseline (408.985 us; speedup 1.0000x reference)
//
#include <hip/hip_runtime.h>

// PointConv: B=4, N=16384, K=32, F=64
// out[p,f] = sum_k ( lrelu(rel(p,k) @ W1 + b1) @ W2 + b2 )[f] * x[idx[p,k], f]
//
// Round 9: kill the remaining exposed latency chains seen in r8 (VALUBusy 36%,
// ~55% stall):
//  - ONE per-lane idx load jm = idx[(p+2)*K+m], 2 iterations ahead, serves
//    BOTH the rel-pos chain and the x-gather row indices. The idx-row s_load
//    path is deleted: row scalars are recovered from jm via 16 ds_bpermute
//    (compile-time offsets; jk was consumed as a VGPR anyway). idx traffic
//    halves, SGPR arrays gone, no SMEM first-touch stall.
//  - pos gathers for p+1 issued at TOP of iter i with addresses from the
//    iteration-old jm (no inline dependent wait); the rel subtraction is
//    deferred to consumption in iter i+1's MFMA phase.
//  - x-gathers issued BEFORE the MFMA phase (~1.3 iter cover to consumption).
//  - __launch_bounds__(256,3): cap ~170 unified regs vs ~135 live set
//    (r7's failure was cap 128 < live ~150; here margin is positive).
// Kept from r8: xvA/xvB double buffer, bfrag-in-LDS conflict-free ds_read_b128,
// f16 packed h, f-interleaved tiles, b2-folded acc init.
// Gating: WRITE_SIZE must stay ~16MB (spill tripwire).

#define NPTS   16384
#define KNB    32
#define F      64
#define BATCH  4
#define LOG2N  14
#define WPTS   8

typedef _Float16 h2     __attribute__((ext_vector_type(2)));
typedef _Float16 h8     __attribute__((ext_vector_type(8)));
typedef float    f32x16 __attribute__((ext_vector_type(16)));

__global__ __launch_bounds__(256, 3) void pointconv_mfma(
    const float* __restrict__ x,
    const float* __restrict__ pos,
    const int*   __restrict__ idx,
    const float* __restrict__ W1,
    const float* __restrict__ b1,
    const float* __restrict__ W2,
    const float* __restrict__ b2,
    float*       __restrict__ out)
{
    // w1p[g/2] = {wx,wx', wy,wy', wz,wz', b1,b1'} for g-pair (f16)
    __shared__ __align__(16) _Float16 w1p[32][8];
    // w2f[hf][t][c][m][j] = f16(W2[16t+8hf+j][2m+c]) — fragment-ordered,
    // lanes read consecutive 16B blocks -> conflict-free ds_read_b128
    __shared__ __align__(16) _Float16 w2f[2][4][2][32][8];

    const int tid = threadIdx.x;
    if (tid < 32) {
        const int g = 2 * tid;
        w1p[tid][0] = (_Float16)W1[0 * F + g]; w1p[tid][1] = (_Float16)W1[0 * F + g + 1];
        w1p[tid][2] = (_Float16)W1[1 * F + g]; w1p[tid][3] = (_Float16)W1[1 * F + g + 1];
        w1p[tid][4] = (_Float16)W1[2 * F + g]; w1p[tid][5] = (_Float16)W1[2 * F + g + 1];
        w1p[tid][6] = (_Float16)b1[g];         w1p[tid][7] = (_Float16)b1[g + 1];
    }
#pragma unroll
    for (int r = 0; r < 16; ++r) {             // 4096 elems, coalesced global read
        const int e = r * 256 + tid;           // e = g*64 + f
        const int g = e >> 6, f = e & 63;
        w2f[(g >> 3) & 1][g >> 4][f & 1][f >> 1][g & 7] = (_Float16)W2[e];
    }
    __syncthreads();

    const int lane = tid & 63;
    const int wv   = tid >> 6;
    const int m    = lane & 31;   // MFMA row (neighbor slot) / f-pair index
    const int hf   = lane >> 5;   // k-half of A/B fragments
    const int voff = hf << 4;     // bpermute byte base: row rA+4*hf lives in lane rA+4*hf

    const float2 b2v = *(const float2*)(b2 + 2 * m);

    const int p0   = (blockIdx.x * 4 + wv) * WPTS;
    const int p0_s = __builtin_amdgcn_readfirstlane(p0);
    const int base = (p0_s >> LOG2N) << LOG2N;                     // b*N
    const float* __restrict__ xb2 = x + (size_t)base * F + 2 * m;  // lane gather base

    const h2 c01 = { (_Float16)0.1f, (_Float16)0.1f };

    // ---- prologue: point p0's rel-pos raw loads, x-gathers; jm for p0+1 ----
    float2 xvA[16], xvB[16];
    float  rlA[6], rlB[6];        // {nbr x,y,z, own x,y,z} raw loads, sub at use
    int    jmA = 0, jmB = 0;      // idx[p][m] pipeline (2 deep)
    {
        const int jm0 = idx[p0_s * KNB + m];
#pragma unroll
        for (int reg = 0; reg < 16; ++reg) {
            const int rA = (reg & 3) + ((reg >> 2) << 3);
            const int jk = __builtin_amdgcn_ds_bpermute(voff + 4 * rA, jm0);
            xvA[reg] = *(const float2*)(xb2 + (size_t)jk * F);
        }
        const int nr0 = base + jm0;
        rlA[0] = pos[nr0 * 3 + 0]; rlA[1] = pos[nr0 * 3 + 1]; rlA[2] = pos[nr0 * 3 + 2];
        rlA[3] = pos[p0_s * 3 + 0]; rlA[4] = pos[p0_s * 3 + 1]; rlA[5] = pos[p0_s * 3 + 2];
        if (WPTS > 1) jmA = idx[(p0_s + 1) * KNB + m];
    }

    // Per iteration (output point p = p0+I):
    //   JM_CUR = idx row p+1 (loaded iter I-1)   JM_NXT <- idx row p+2
    //   RL_CUR = pos raw loads for p (iter I-1)  RL_NXT <- pos loads for p+1
    //   XV_CUR = x rows for p (iter I-1)         XV_NXT <- x rows for p+1
#define POINT_BODY(XV_CUR, XV_NXT, JM_CUR, JM_NXT, RL_CUR, RL_NXT, I)         \
    {                                                                         \
        const int p_s = p0_s + (I);                                           \
        /* (1) idx row p+2, per-lane, no deps */                              \
        if ((I) + 2 < WPTS) JM_NXT = idx[(p_s + 2) * KNB + m];                \
        /* (2) pos raw loads for p+1 (JM_CUR is an iteration old: ready) */   \
        if ((I) + 1 < WPTS) {                                                 \
            const int nr = base + JM_CUR;                                     \
            RL_NXT[0] = pos[nr * 3 + 0];                                      \
            RL_NXT[1] = pos[nr * 3 + 1];                                      \
            RL_NXT[2] = pos[nr * 3 + 2];                                      \
            RL_NXT[3] = pos[(p_s + 1) * 3 + 0];                               \
            RL_NXT[4] = pos[(p_s + 1) * 3 + 1];                               \
            RL_NXT[5] = pos[(p_s + 1) * 3 + 2];                               \
        }                                                                     \
        /* (3) x-gathers for p+1: rows from JM_CUR via bpermute */            \
        if ((I) + 1 < WPTS) {                                                 \
            _Pragma("unroll")                                                 \
            for (int reg = 0; reg < 16; ++reg) {                              \
                const int rA = (reg & 3) + ((reg >> 2) << 3);                 \
                const int jk = __builtin_amdgcn_ds_bpermute(voff + 4 * rA, JM_CUR); \
                XV_NXT[reg] = *(const float2*)(xb2 + (size_t)jk * F);         \
            }                                                                 \
        }                                                                     \
        /* (4) MFMA phase for p (RL_CUR loads are an iteration old) */        \
        const float rx = RL_CUR[3] - RL_CUR[0];                               \
        const float ry = RL_CUR[4] - RL_CUR[1];                               \
        const float rz = RL_CUR[5] - RL_CUR[2];                               \
        f32x16 acc0, acc1;                                                    \
        _Pragma("unroll")                                                     \
        for (int r = 0; r < 16; ++r) { acc0[r] = b2v.x; acc1[r] = b2v.y; }    \
        const h2 rxp = { (_Float16)rx, (_Float16)rx };                        \
        const h2 ryp = { (_Float16)ry, (_Float16)ry };                        \
        const h2 rzp = { (_Float16)rz, (_Float16)rz };                        \
        _Pragma("unroll")                                                     \
        for (int t = 0; t < 4; ++t) {                                         \
            h8 af;                                                            \
            _Pragma("unroll")                                                 \
            for (int jj = 0; jj < 4; ++jj) {                                  \
                const int g2 = 8 * t + 4 * hf + jj;                           \
                const h8 w = *(const h8*)&w1p[g2][0];                         \
                const h2 wx = __builtin_shufflevector(w, w, 0, 1);            \
                const h2 wy = __builtin_shufflevector(w, w, 2, 3);            \
                const h2 wz = __builtin_shufflevector(w, w, 4, 5);            \
                const h2 bb = __builtin_shufflevector(w, w, 6, 7);            \
                h2 hv = bb + rxp * wx;                                        \
                hv = hv + ryp * wy;                                           \
                hv = hv + rzp * wz;                                           \
                hv = __builtin_elementwise_max(hv, hv * c01);                 \
                af[2 * jj]     = hv[0];                                       \
                af[2 * jj + 1] = hv[1];                                       \
            }                                                                 \
            const h8 bf0 = *(const h8*)&w2f[hf][t][0][m][0];                  \
            const h8 bf1 = *(const h8*)&w2f[hf][t][1][m][0];                  \
            acc0 = __builtin_amdgcn_mfma_f32_32x32x16_f16(af, bf0, acc0, 0, 0, 0); \
            acc1 = __builtin_amdgcn_mfma_f32_32x32x16_f16(af, bf1, acc1, 0, 0, 0); \
        }                                                                     \
        /* (5) epilogue: consume XV_CUR (issued one iteration ago) */         \
        float s0 = 0.f, s1 = 0.f;                                             \
        _Pragma("unroll")                                                     \
        for (int reg = 0; reg < 16; ++reg) {                                  \
            s0 = fmaf(acc0[reg], XV_CUR[reg].x, s0);                          \
            s1 = fmaf(acc1[reg], XV_CUR[reg].y, s1);                          \
        }                                                                     \
        s0 += __shfl_xor(s0, 32);                                             \
        s1 += __shfl_xor(s1, 32);                                             \
        if (hf == 0)                                                          \
            *(float2*)(out + (size_t)p_s * F + 2 * m) = make_float2(s0, s1);  \
    }

#pragma unroll 1
    for (int io = 0; io < WPTS; io += 2) {
        POINT_BODY(xvA, xvB, jmA, jmB, rlA, rlB, io);
        POINT_BODY(xvB, xvA, jmB, jmA, rlB, rlA, io + 1);
    }
#undef POINT_BODY
}

extern "C" void kernel_launch(void* const* d_in, const int* in_sizes, int n_in,
                              void* d_out, int out_size, void* d_ws, size_t ws_size,
                              hipStream_t stream) {
    const float* x   = (const float*)d_in[0];
    const float* pos = (const float*)d_in[1];
    const int*   idx = (const int*)  d_in[2];
    const float* W1  = (const float*)d_in[3];
    const float* b1  = (const float*)d_in[4];
    const float* W2  = (const float*)d_in[5];
    const float* b2  = (const float*)d_in[6];
    float* out = (float*)d_out;

    dim3 grid((BATCH * NPTS) / (4 * WPTS));   // 4 waves/block, WPTS points/wave
    dim3 block(256);
    pointconv_mfma<<<grid, block, 0, stream>>>(x, pos, idx, W1, b1, W2, b2, out);
}

// Round 5
// 137.926 us; speedup vs baseline: 2.9652x; 2.9652x over previous
//
#include <hip/hip_runtime.h>

// PointConv: B=4, N=16384, K=32, F=64
// out[p,f] = sum_k ( lrelu(rel(p,k) @ W1 + b1) @ W2 + b2 )[f] * x[idx[p,k], f]
//
// Round 10: r9's 2-deep pipeline was sound but (256,3) spilled (3rd failed
// cap: only (256,2) fits the ~190-reg live set -> occupancy lever closed).
// This round: r9 structure at (256,2) + VALU-count attack. r8's counters
// implied ~470 VALU insts/point; ~110 of them are 64-bit gather address
// chains from (size_t) casts. All gathers now use uniform-pointer +
// uint32 element offsets (max 4.2M << 2^32) so the compiler emits
// global_load ... saddr with a 32-bit voffset: ~2 VALU/gather instead of 4-5.
//  - x-gather:  off = (base+jk)<<6 | 2m      (uint32)
//  - pos loads: off = 3*nr + c               (uint32)
//  - idx loads: scalar part folds into saddr, voffset = 4m (hoisted)
//  - out store: scalar part in saddr, voffset = 8m (hoisted)
// Kept from r9: single per-lane idx load 2 iters ahead serving both rel-pos
// and x-rows (recovered via 16 ds_bpermute), pos loads issued with
// iteration-old addresses, x-gathers before MFMA phase, bfrag-in-LDS,
// f16 packed h, b2-folded acc init.
// Gating: WRITE_SIZE ~16MB (spill tripwire; r6/r7/r9 all tripped it).

#define NPTS   16384
#define KNB    32
#define F      64
#define BATCH  4
#define LOG2N  14
#define WPTS   8

typedef _Float16 h2     __attribute__((ext_vector_type(2)));
typedef _Float16 h8     __attribute__((ext_vector_type(8)));
typedef float    f32x16 __attribute__((ext_vector_type(16)));

__global__ __launch_bounds__(256, 2) void pointconv_mfma(
    const float* __restrict__ x,
    const float* __restrict__ pos,
    const int*   __restrict__ idx,
    const float* __restrict__ W1,
    const float* __restrict__ b1,
    const float* __restrict__ W2,
    const float* __restrict__ b2,
    float*       __restrict__ out)
{
    // w1p[g/2] = {wx,wx', wy,wy', wz,wz', b1,b1'} for g-pair (f16)
    __shared__ __align__(16) _Float16 w1p[32][8];
    // w2f[hf][t][c][m][j] = f16(W2[16t+8hf+j][2m+c]) — fragment-ordered,
    // lanes read consecutive 16B blocks -> conflict-free ds_read_b128
    __shared__ __align__(16) _Float16 w2f[2][4][2][32][8];

    const int tid = threadIdx.x;
    if (tid < 32) {
        const int g = 2 * tid;
        w1p[tid][0] = (_Float16)W1[0 * F + g]; w1p[tid][1] = (_Float16)W1[0 * F + g + 1];
        w1p[tid][2] = (_Float16)W1[1 * F + g]; w1p[tid][3] = (_Float16)W1[1 * F + g + 1];
        w1p[tid][4] = (_Float16)W1[2 * F + g]; w1p[tid][5] = (_Float16)W1[2 * F + g + 1];
        w1p[tid][6] = (_Float16)b1[g];         w1p[tid][7] = (_Float16)b1[g + 1];
    }
#pragma unroll
    for (int r = 0; r < 16; ++r) {             // 4096 elems, coalesced global read
        const int e = r * 256 + tid;           // e = g*64 + f
        const int g = e >> 6, f = e & 63;
        w2f[(g >> 3) & 1][g >> 4][f & 1][f >> 1][g & 7] = (_Float16)W2[e];
    }
    __syncthreads();

    const int lane = tid & 63;
    const int wv   = tid >> 6;
    const int m    = lane & 31;   // MFMA row (neighbor slot) / f-pair index
    const int hf   = lane >> 5;   // k-half of A/B fragments
    const int voff = hf << 4;     // bpermute byte base (source lane 4*hf + rA)

    const float2 b2v = *(const float2*)(b2 + 2 * m);

    const int p0   = (blockIdx.x * 4 + wv) * WPTS;
    const int p0_s = __builtin_amdgcn_readfirstlane(p0);
    const int base = (p0_s >> LOG2N) << LOG2N;                     // b*N
    const uint32_t m2 = 2u * (uint32_t)m;                          // f-pair offset

    const h2 c01 = { (_Float16)0.1f, (_Float16)0.1f };

    // ---- prologue: point p0's rel-pos raw loads, x-gathers; jm for p0+1 ----
    float2 xvA[16], xvB[16];
    float  rlA[6], rlB[6];        // {nbr x,y,z, own x,y,z} raw loads, sub at use
    int    jmA = 0, jmB = 0;      // idx[p][m] pipeline (2 deep)
    {
        const int jm0 = idx[(uint32_t)(p0_s * KNB) + (uint32_t)m];
#pragma unroll
        for (int reg = 0; reg < 16; ++reg) {
            const int rA = (reg & 3) + ((reg >> 2) << 3);
            const int jk = __builtin_amdgcn_ds_bpermute(voff + 4 * rA, jm0);
            const uint32_t xo = ((uint32_t)(base + jk) << 6) + m2;
            xvA[reg] = *(const float2*)(x + xo);
        }
        const uint32_t nr3 = 3u * (uint32_t)(base + jm0);
        const uint32_t pp3 = 3u * (uint32_t)p0_s;
        rlA[0] = pos[nr3];     rlA[1] = pos[nr3 + 1]; rlA[2] = pos[nr3 + 2];
        rlA[3] = pos[pp3];     rlA[4] = pos[pp3 + 1]; rlA[5] = pos[pp3 + 2];
        if (WPTS > 1) jmA = idx[(uint32_t)((p0_s + 1) * KNB) + (uint32_t)m];
    }

    // Per iteration (output point p = p0+I):
    //   JM_CUR = idx row p+1 (loaded iter I-1)   JM_NXT <- idx row p+2
    //   RL_CUR = pos raw loads for p (iter I-1)  RL_NXT <- pos loads for p+1
    //   XV_CUR = x rows for p (iter I-1)         XV_NXT <- x rows for p+1
#define POINT_BODY(XV_CUR, XV_NXT, JM_CUR, JM_NXT, RL_CUR, RL_NXT, I)         \
    {                                                                         \
        const int p_s = p0_s + (I);                                           \
        /* (1) idx row p+2, per-lane, no deps (saddr + hoisted 4m voffset) */ \
        if ((I) + 2 < WPTS)                                                   \
            JM_NXT = idx[(uint32_t)((p_s + 2) * KNB) + (uint32_t)m];          \
        /* (2) pos raw loads for p+1 (JM_CUR is an iteration old: ready) */   \
        if ((I) + 1 < WPTS) {                                                 \
            const uint32_t nr3 = 3u * (uint32_t)(base + JM_CUR);              \
            const uint32_t pp3 = 3u * (uint32_t)(p_s + 1);                    \
            RL_NXT[0] = pos[nr3];     RL_NXT[1] = pos[nr3 + 1];               \
            RL_NXT[2] = pos[nr3 + 2];                                         \
            RL_NXT[3] = pos[pp3];     RL_NXT[4] = pos[pp3 + 1];               \
            RL_NXT[5] = pos[pp3 + 2];                                         \
        }                                                                     \
        /* (3) x-gathers for p+1: rows from JM_CUR via bpermute, 32b offs */  \
        if ((I) + 1 < WPTS) {                                                 \
            _Pragma("unroll")                                                 \
            for (int reg = 0; reg < 16; ++reg) {                              \
                const int rA = (reg & 3) + ((reg >> 2) << 3);                 \
                const int jk = __builtin_amdgcn_ds_bpermute(voff + 4 * rA, JM_CUR); \
                const uint32_t xo = ((uint32_t)(base + jk) << 6) + m2;        \
                XV_NXT[reg] = *(const float2*)(x + xo);                       \
            }                                                                 \
        }                                                                     \
        /* (4) MFMA phase for p (RL_CUR loads are an iteration old) */        \
        const float rx = RL_CUR[3] - RL_CUR[0];                               \
        const float ry = RL_CUR[4] - RL_CUR[1];                               \
        const float rz = RL_CUR[5] - RL_CUR[2];                               \
        f32x16 acc0, acc1;                                                    \
        _Pragma("unroll")                                                     \
        for (int r = 0; r < 16; ++r) { acc0[r] = b2v.x; acc1[r] = b2v.y; }    \
        const h2 rxp = { (_Float16)rx, (_Float16)rx };                        \
        const h2 ryp = { (_Float16)ry, (_Float16)ry };                        \
        const h2 rzp = { (_Float16)rz, (_Float16)rz };                        \
        _Pragma("unroll")                                                     \
        for (int t = 0; t < 4; ++t) {                                         \
            h8 af;                                                            \
            _Pragma("unroll")                                                 \
            for (int jj = 0; jj < 4; ++jj) {                                  \
                const int g2 = 8 * t + 4 * hf + jj;                           \
                const h8 w = *(const h8*)&w1p[g2][0];                         \
                const h2 wx = __builtin_shufflevector(w, w, 0, 1);            \
                const h2 wy = __builtin_shufflevector(w, w, 2, 3);            \
                const h2 wz = __builtin_shufflevector(w, w, 4, 5);            \
                const h2 bb = __builtin_shufflevector(w, w, 6, 7);            \
                h2 hv = bb + rxp * wx;                                        \
                hv = hv + ryp * wy;                                           \
                hv = hv + rzp * wz;                                           \
                hv = __builtin_elementwise_max(hv, hv * c01);                 \
                af[2 * jj]     = hv[0];                                       \
                af[2 * jj + 1] = hv[1];                                       \
            }                                                                 \
            const h8 bf0 = *(const h8*)&w2f[hf][t][0][m][0];                  \
            const h8 bf1 = *(const h8*)&w2f[hf][t][1][m][0];                  \
            acc0 = __builtin_amdgcn_mfma_f32_32x32x16_f16(af, bf0, acc0, 0, 0, 0); \
            acc1 = __builtin_amdgcn_mfma_f32_32x32x16_f16(af, bf1, acc1, 0, 0, 0); \
        }                                                                     \
        /* (5) epilogue: consume XV_CUR (issued one iteration ago) */         \
        float s0 = 0.f, s1 = 0.f;                                             \
        _Pragma("unroll")                                                     \
        for (int reg = 0; reg < 16; ++reg) {                                  \
            s0 = fmaf(acc0[reg], XV_CUR[reg].x, s0);                          \
            s1 = fmaf(acc1[reg], XV_CUR[reg].y, s1);                          \
        }                                                                     \
        s0 += __shfl_xor(s0, 32);                                             \
        s1 += __shfl_xor(s1, 32);                                             \
        if (hf == 0)                                                          \
            *(float2*)(out + (uint32_t)(p_s * F) + m2) = make_float2(s0, s1); \
    }

#pragma unroll 1
    for (int io = 0; io < WPTS; io += 2) {
        POINT_BODY(xvA, xvB, jmA, jmB, rlA, rlB, io);
        POINT_BODY(xvB, xvA, jmB, jmA, rlB, rlA, io + 1);
    }
#undef POINT_BODY
}

extern "C" void kernel_launch(void* const* d_in, const int* in_sizes, int n_in,
                              void* d_out, int out_size, void* d_ws, size_t ws_size,
                              hipStream_t stream) {
    const float* x   = (const float*)d_in[0];
    const float* pos = (const float*)d_in[1];
    const int*   idx = (const int*)  d_in[2];
    const float* W1  = (const float*)d_in[3];
    const float* b1  = (const float*)d_in[4];
    const float* W2  = (const float*)d_in[5];
    const float* b2  = (const float*)d_in[6];
    float* out = (float*)d_out;

    dim3 grid((BATCH * NPTS) / (4 * WPTS));   // 4 waves/block, WPTS points/wave
    dim3 block(256);
    pointconv_mfma<<<grid, block, 0, stream>>>(x, pos, idx, W1, b1, W2, b2, out);
}

// Round 7
// 137.309 us; speedup vs baseline: 2.9786x; 1.0045x over previous
//
#include <hip/hip_runtime.h>

// PointConv: B=4, N=16384, K=32, F=64
// out[p,f] = sum_k ( lrelu(rel(p,k) @ W1 + b1) @ W2 + b2 )[f] * x[idx[p,k], f]
//
// Round 11 (re-run; previous attempt died to container infra, not the kernel).
// r10 showed VALU-count cuts don't move dur (72us, VALUBusy 36->31%, dur flat)
// -> still latency-bound. Remaining unpipelined latency: 24 ds_read per point
// on the MFMA critical path (16 w1p + 8 bfrag, ~120cyc each), all
// LOOP-INVARIANT — re-read per point only because r6 evicted them chasing
// occupancy (lever proven closed by r6/r7/r9 spills). At (256,2) the unified
// budget is 256 regs; r10 used ~160. Spend the headroom:
//  - w1r[16] (h8, 64 VGPRs): all W1/b1 fragment rows hoisted pre-loop
//  - bfrag[4][2] (h8, 32 VGPRs): W2 fragments hoisted pre-loop (r5 style)
//  - per-point LDS ops: 24 reads + 16 bpermute -> 16 bpermute only;
//    MFMA phase is pure register VALU+MFMA
// Kept from r10: 2-deep jm pipeline (one idx load serving rel-pos + x-rows via
// bpermute), iteration-old pos addresses, x-gathers before MFMA, 32-bit saddr
// addressing, f16 packed h, b2-folded acc init, xvA/xvB double buffer.
// Gating: WRITE_SIZE ~16MB (spill tripwire). Live-set estimate ~222/256.

#define NPTS   16384
#define KNB    32
#define F      64
#define BATCH  4
#define LOG2N  14
#define WPTS   8

typedef _Float16 h2     __attribute__((ext_vector_type(2)));
typedef _Float16 h8     __attribute__((ext_vector_type(8)));
typedef float    f32x16 __attribute__((ext_vector_type(16)));

__global__ __launch_bounds__(256, 2) void pointconv_mfma(
    const float* __restrict__ x,
    const float* __restrict__ pos,
    const int*   __restrict__ idx,
    const float* __restrict__ W1,
    const float* __restrict__ b1,
    const float* __restrict__ W2,
    const float* __restrict__ b2,
    float*       __restrict__ out)
{
    // w1p[g/2] = {wx,wx', wy,wy', wz,wz', b1,b1'} for g-pair (f16)
    __shared__ __align__(16) _Float16 w1p[32][8];
    // w2f[hf][t][c][m][j] = f16(W2[16t+8hf+j][2m+c]) — fragment-ordered,
    // lanes read consecutive 16B blocks -> conflict-free ds_read_b128
    __shared__ __align__(16) _Float16 w2f[2][4][2][32][8];

    const int tid = threadIdx.x;
    if (tid < 32) {
        const int g = 2 * tid;
        w1p[tid][0] = (_Float16)W1[0 * F + g]; w1p[tid][1] = (_Float16)W1[0 * F + g + 1];
        w1p[tid][2] = (_Float16)W1[1 * F + g]; w1p[tid][3] = (_Float16)W1[1 * F + g + 1];
        w1p[tid][4] = (_Float16)W1[2 * F + g]; w1p[tid][5] = (_Float16)W1[2 * F + g + 1];
        w1p[tid][6] = (_Float16)b1[g];         w1p[tid][7] = (_Float16)b1[g + 1];
    }
#pragma unroll
    for (int r = 0; r < 16; ++r) {             // 4096 elems, coalesced global read
        const int e = r * 256 + tid;           // e = g*64 + f
        const int g = e >> 6, f = e & 63;
        w2f[(g >> 3) & 1][g >> 4][f & 1][f >> 1][g & 7] = (_Float16)W2[e];
    }
    __syncthreads();

    const int lane = tid & 63;
    const int wv   = tid >> 6;
    const int m    = lane & 31;   // MFMA row (neighbor slot) / f-pair index
    const int hf   = lane >> 5;   // k-half of A/B fragments
    const int voff = hf << 4;     // bpermute byte base (source lane 4*hf + rA)

    // ---- loop-invariant fragments -> registers (once) ----
    // w1r[4t+jj] = w1p[8t+4hf+jj]  (wx,wy,wz,b1 pairs for this lane's K-slots)
    h8 w1r[16];
#pragma unroll
    for (int t = 0; t < 4; ++t)
#pragma unroll
        for (int jj = 0; jj < 4; ++jj)
            w1r[4 * t + jj] = *(const h8*)&w1p[8 * t + 4 * hf + jj][0];
    // bfrag[t][c]: W2 B-operand fragments (conflict-free b128, read once)
    h8 bfrag[4][2];
#pragma unroll
    for (int t = 0; t < 4; ++t)
#pragma unroll
        for (int c = 0; c < 2; ++c)
            bfrag[t][c] = *(const h8*)&w2f[hf][t][c][m][0];

    const float2 b2v = *(const float2*)(b2 + 2 * m);

    const int p0   = (blockIdx.x * 4 + wv) * WPTS;
    const int p0_s = __builtin_amdgcn_readfirstlane(p0);
    const int base = (p0_s >> LOG2N) << LOG2N;                     // b*N
    const uint32_t m2 = 2u * (uint32_t)m;                          // f-pair offset

    const h2 c01 = { (_Float16)0.1f, (_Float16)0.1f };

    // ---- prologue: point p0's rel-pos raw loads, x-gathers; jm for p0+1 ----
    float2 xvA[16], xvB[16];
    float  rlA[6], rlB[6];        // {nbr x,y,z, own x,y,z} raw loads, sub at use
    int    jmA = 0, jmB = 0;      // idx[p][m] pipeline (2 deep)
    {
        const int jm0 = idx[(uint32_t)(p0_s * KNB) + (uint32_t)m];
#pragma unroll
        for (int reg = 0; reg < 16; ++reg) {
            const int rA = (reg & 3) + ((reg >> 2) << 3);
            const int jk = __builtin_amdgcn_ds_bpermute(voff + 4 * rA, jm0);
            const uint32_t xo = ((uint32_t)(base + jk) << 6) + m2;
            xvA[reg] = *(const float2*)(x + xo);
        }
        const uint32_t nr3 = 3u * (uint32_t)(base + jm0);
        const uint32_t pp3 = 3u * (uint32_t)p0_s;
        rlA[0] = pos[nr3];     rlA[1] = pos[nr3 + 1]; rlA[2] = pos[nr3 + 2];
        rlA[3] = pos[pp3];     rlA[4] = pos[pp3 + 1]; rlA[5] = pos[pp3 + 2];
        if (WPTS > 1) jmA = idx[(uint32_t)((p0_s + 1) * KNB) + (uint32_t)m];
    }

    // Per iteration (output point p = p0+I):
    //   JM_CUR = idx row p+1 (loaded iter I-1)   JM_NXT <- idx row p+2
    //   RL_CUR = pos raw loads for p (iter I-1)  RL_NXT <- pos loads for p+1
    //   XV_CUR = x rows for p (iter I-1)         XV_NXT <- x rows for p+1
#define POINT_BODY(XV_CUR, XV_NXT, JM_CUR, JM_NXT, RL_CUR, RL_NXT, I)         \
    {                                                                         \
        const int p_s = p0_s + (I);                                           \
        /* (1) idx row p+2, per-lane, no deps (saddr + hoisted 4m voffset) */ \
        if ((I) + 2 < WPTS)                                                   \
            JM_NXT = idx[(uint32_t)((p_s + 2) * KNB) + (uint32_t)m];          \
        /* (2) pos raw loads for p+1 (JM_CUR is an iteration old: ready) */   \
        if ((I) + 1 < WPTS) {                                                 \
            const uint32_t nr3 = 3u * (uint32_t)(base + JM_CUR);              \
            const uint32_t pp3 = 3u * (uint32_t)(p_s + 1);                    \
            RL_NXT[0] = pos[nr3];     RL_NXT[1] = pos[nr3 + 1];               \
            RL_NXT[2] = pos[nr3 + 2];                                         \
            RL_NXT[3] = pos[pp3];     RL_NXT[4] = pos[pp3 + 1];               \
            RL_NXT[5] = pos[pp3 + 2];                                         \
        }                                                                     \
        /* (3) x-gathers for p+1: rows from JM_CUR via bpermute, 32b offs */  \
        if ((I) + 1 < WPTS) {                                                 \
            _Pragma("unroll")                                                 \
            for (int reg = 0; reg < 16; ++reg) {                              \
                const int rA = (reg & 3) + ((reg >> 2) << 3);                 \
                const int jk = __builtin_amdgcn_ds_bpermute(voff + 4 * rA, JM_CUR); \
                const uint32_t xo = ((uint32_t)(base + jk) << 6) + m2;        \
                XV_NXT[reg] = *(const float2*)(x + xo);                       \
            }                                                                 \
        }                                                                     \
        /* (4) MFMA phase for p — pure register VALU+MFMA, no LDS */          \
        const float rx = RL_CUR[3] - RL_CUR[0];                               \
        const float ry = RL_CUR[4] - RL_CUR[1];                               \
        const float rz = RL_CUR[5] - RL_CUR[2];                               \
        f32x16 acc0, acc1;                                                    \
        _Pragma("unroll")                                                     \
        for (int r = 0; r < 16; ++r) { acc0[r] = b2v.x; acc1[r] = b2v.y; }    \
        const h2 rxp = { (_Float16)rx, (_Float16)rx };                        \
        const h2 ryp = { (_Float16)ry, (_Float16)ry };                        \
        const h2 rzp = { (_Float16)rz, (_Float16)rz };                        \
        _Pragma("unroll")                                                     \
        for (int t = 0; t < 4; ++t) {                                         \
            h8 af;                                                            \
            _Pragma("unroll")                                                 \
            for (int jj = 0; jj < 4; ++jj) {                                  \
                const h8 w = w1r[4 * t + jj];                                 \
                const h2 wx = __builtin_shufflevector(w, w, 0, 1);            \
                const h2 wy = __builtin_shufflevector(w, w, 2, 3);            \
                const h2 wz = __builtin_shufflevector(w, w, 4, 5);            \
                const h2 bb = __builtin_shufflevector(w, w, 6, 7);            \
                h2 hv = bb + rxp * wx;                                        \
                hv = hv + ryp * wy;                                           \
                hv = hv + rzp * wz;                                           \
                hv = __builtin_elementwise_max(hv, hv * c01);                 \
                af[2 * jj]     = hv[0];                                       \
                af[2 * jj + 1] = hv[1];                                       \
            }                                                                 \
            acc0 = __builtin_amdgcn_mfma_f32_32x32x16_f16(af, bfrag[t][0], acc0, 0, 0, 0); \
            acc1 = __builtin_amdgcn_mfma_f32_32x32x16_f16(af, bfrag[t][1], acc1, 0, 0, 0); \
        }                                                                     \
        /* (5) epilogue: consume XV_CUR (issued one iteration ago) */         \
        float s0 = 0.f, s1 = 0.f;                                             \
        _Pragma("unroll")                                                     \
        for (int reg = 0; reg < 16; ++reg) {                                  \
            s0 = fmaf(acc0[reg], XV_CUR[reg].x, s0);                          \
            s1 = fmaf(acc1[reg], XV_CUR[reg].y, s1);                          \
        }                                                                     \
        s0 += __shfl_xor(s0, 32);                                             \
        s1 += __shfl_xor(s1, 32);                                             \
        if (hf == 0)                                                          \
            *(float2*)(out + (uint32_t)(p_s * F) + m2) = make_float2(s0, s1); \
    }

#pragma unroll 1
    for (int io = 0; io < WPTS; io += 2) {
        POINT_BODY(xvA, xvB, jmA, jmB, rlA, rlB, io);
        POINT_BODY(xvB, xvA, jmB, jmA, rlB, rlA, io + 1);
    }
#undef POINT_BODY
}

extern "C" void kernel_launch(void* const* d_in, const int* in_sizes, int n_in,
                              void* d_out, int out_size, void* d_ws, size_t ws_size,
                              hipStream_t stream) {
    const float* x   = (const float*)d_in[0];
    const float* pos = (const float*)d_in[1];
    const int*   idx = (const int*)  d_in[2];
    const float* W1  = (const float*)d_in[3];
    const float* b1  = (const float*)d_in[4];
    const float* W2  = (const float*)d_in[5];
    const float* b2  = (const float*)d_in[6];
    float* out = (float*)d_out;

    dim3 grid((BATCH * NPTS) / (4 * WPTS));   // 4 waves/block, WPTS points/wave
    dim3 block(256);
    pointconv_mfma<<<grid, block, 0, stream>>>(x, pos, idx, W1, b1, W2, b2, out);
}